// Round 2
// baseline (1595.154 us; speedup 1.0000x reference)
//
#include <hip/hip_runtime.h>

#define NRES 384
#define CZ 128
#define NH 4
#define CH 32
#define NN (NRES * NRES)
#define NNCZ ((size_t)NN * CZ)

typedef unsigned short u16;
typedef __attribute__((ext_vector_type(4))) unsigned short us4;
typedef __attribute__((ext_vector_type(8))) unsigned short us8;

__device__ __forceinline__ float bf2f(u16 u) {
  return __uint_as_float(((unsigned)u) << 16);
}
__device__ __forceinline__ u16 f2bf(float f) {
  unsigned u = __float_as_uint(f);
  u += 0x7fffu + ((u >> 16) & 1u);  // RTNE
  return (u16)(u >> 16);
}

template<bool F32>
__device__ __forceinline__ float ld1(const void* p, size_t i) {
  if constexpr (F32) return ((const float*)p)[i];
  else return bf2f(((const u16*)p)[i]);
}

// load 8 consecutive elements (i multiple of 8) as fp32
template<bool F32>
__device__ __forceinline__ void ld8(const void* p, size_t i, float o[8]) {
  if constexpr (F32) {
    const float4 a = *(const float4*)((const float*)p + i);
    const float4 b = *(const float4*)((const float*)p + i + 4);
    o[0] = a.x; o[1] = a.y; o[2] = a.z; o[3] = a.w;
    o[4] = b.x; o[5] = b.y; o[6] = b.z; o[7] = b.w;
  } else {
    const us8 v = *(const us8*)((const u16*)p + i);
    #pragma unroll
    for (int u = 0; u < 8; ++u) o[u] = bf2f(v[u]);
  }
}

// ---------------------------------------------------------------------------
// Probe: decide input dtype from z's bit patterns. bf16 N(0,1): exponent
// field clustered near 0x7F. fp32 read as u16 halves: ~half the samples have
// uniform-random exponents. Vote over 256 samples.
// ---------------------------------------------------------------------------
__global__ void k_probe(const u16* __restrict__ z, int* __restrict__ flag) {
  int weird = 0;
  for (int i = threadIdx.x; i < 256; i += 64) {
    const int e = (z[i] >> 7) & 0xFF;
    if (e < 0x70 || e > 0x8F) weird++;
  }
  #pragma unroll
  for (int m = 1; m < 64; m <<= 1) weird += __shfl_xor(weird, m, 64);
  if (threadIdx.x == 0) *flag = (weird >= 16) ? 1 : 0;
}

// ---------------------------------------------------------------------------
// K1: LayerNorm + q/k/v/g projections + tri_bias. 16 rows / 256-thread block.
// Weights converted to bf16 while staging into LDS. q pre-scaled by CH^-0.5;
// g = sigmoid(zn@w_g + b_g). Intermediates in ws are always bf16 (tri fp32).
// ---------------------------------------------------------------------------
template<bool F32>
__global__ __launch_bounds__(256) void k_ln_proj(
    const void* __restrict__ z, const void* __restrict__ gma, const void* __restrict__ bta,
    const void* __restrict__ wbias, const void* __restrict__ wq, const void* __restrict__ wk,
    const void* __restrict__ wv, const void* __restrict__ wg, const void* __restrict__ bg,
    u16* __restrict__ qb, u16* __restrict__ kb, u16* __restrict__ vb, u16* __restrict__ gb,
    float* __restrict__ tri, const int* __restrict__ flag)
{
  if ((*flag != 0) != F32) return;
  __shared__ __align__(16) float zn[16][132];
  __shared__ __align__(16) u16 wl[CZ * CZ];
  const int t = threadIdx.x;
  const int lane = t & 63;
  const int wid = t >> 6;
  const int rowBase = blockIdx.x * 16;

  // LayerNorm: wave `wid` handles local rows wid*4..wid*4+3 (2 ch/lane)
  for (int rr = 0; rr < 4; ++rr) {
    const int rloc = wid * 4 + rr;
    const size_t row = (size_t)(rowBase + rloc);
    const int c0 = lane * 2;
    const float x0 = ld1<F32>(z, row * CZ + c0);
    const float x1 = ld1<F32>(z, row * CZ + c0 + 1);
    float s = x0 + x1;
    float q2 = x0 * x0 + x1 * x1;
    #pragma unroll
    for (int m = 1; m < 64; m <<= 1) {
      s  += __shfl_xor(s, m, 64);
      q2 += __shfl_xor(q2, m, 64);
    }
    const float mu = s * (1.0f / CZ);
    const float rs = rsqrtf(q2 * (1.0f / CZ) - mu * mu + 1e-5f);
    zn[rloc][c0]     = (x0 - mu) * rs * ld1<F32>(gma, c0)     + ld1<F32>(bta, c0);
    zn[rloc][c0 + 1] = (x1 - mu) * rs * ld1<F32>(gma, c0 + 1) + ld1<F32>(bta, c0 + 1);
  }
  __syncthreads();

  const int rloc = t >> 4;
  const int ob = (t & 15) * 8;
  const size_t rowg = (size_t)(rowBase + rloc) * CZ;

  for (int arr = 0; arr < 4; ++arr) {
    const void* W = (arr == 0) ? wq : (arr == 1) ? wk : (arr == 2) ? wv : wg;
    #pragma unroll
    for (int it = 0; it < 8; ++it) {
      const int idx = (t + it * 256) * 8;   // 2048 chunks of 8
      float tmp[8];
      ld8<F32>(W, idx, tmp);
      us8 o;
      #pragma unroll
      for (int u = 0; u < 8; ++u) o[u] = f2bf(tmp[u]);
      *(us8*)&wl[idx] = o;
    }
    __syncthreads();

    float acc[8] = {0.f, 0.f, 0.f, 0.f, 0.f, 0.f, 0.f, 0.f};
    #pragma unroll 4
    for (int c = 0; c < CZ; ++c) {
      const float zv = zn[rloc][c];
      const us8 w8 = *(const us8*)&wl[c * CZ + ob];
      #pragma unroll
      for (int u = 0; u < 8; ++u) acc[u] += zv * bf2f(w8[u]);
    }
    if (arr == 0) {
      #pragma unroll
      for (int u = 0; u < 8; ++u) acc[u] *= 0.17677669529663687f;  // CH^-0.5
    } else if (arr == 3) {
      #pragma unroll
      for (int u = 0; u < 8; ++u) {
        const float x = acc[u] + ld1<F32>(bg, ob + u);
        acc[u] = 1.0f / (1.0f + __expf(-x));
      }
    }
    us8 o8;
    #pragma unroll
    for (int u = 0; u < 8; ++u) o8[u] = f2bf(acc[u]);
    u16* dstb = (arr == 0) ? qb : (arr == 1) ? kb : (arr == 2) ? vb : gb;
    *(us8*)&dstb[rowg + ob] = o8;
    __syncthreads();  // before wl is overwritten
  }

  // tri_bias[h, i*N+j] = sum_c zn * w_bias[c,h]  (fp32)
  if (t < 64) {
    const int rl = t >> 2, hh = t & 3;
    float acc = 0.f;
    for (int c = 0; c < CZ; ++c) acc += zn[rl][c] * ld1<F32>(wbias, c * NH + hh);
    tri[(size_t)hh * NN + rowBase + rl] = acc;
  }
}

// ---------------------------------------------------------------------------
// K2: attention per (i,h). 512 threads = 8 waves; wave owns rows j=wid+8t.
// K in LDS [k][d] pad 36; V^T [d][k] pad 388. Softmax wave-wide; gating fused.
// Output aliases q buffer (same slice, consumed before written).
// ---------------------------------------------------------------------------
template<bool F32>
__global__ __launch_bounds__(512) void k_attn(
    const u16* __restrict__ qb, const u16* __restrict__ kb, const u16* __restrict__ vb,
    const u16* __restrict__ gb, const float* __restrict__ tri, const void* __restrict__ msk,
    u16* __restrict__ ogb, const int* __restrict__ flag)
{
  if ((*flag != 0) != F32) return;
  __shared__ __align__(16) u16 Kl[NRES * 36];
  __shared__ __align__(16) u16 Vt[CH * 388];
  __shared__ __align__(16) float al[8][NRES];
  const int t = threadIdx.x;
  const int i = blockIdx.x >> 2;
  const int h = blockIdx.x & 3;
  const size_t base_i = (size_t)i * NRES;

  for (int it = 0; it < 6; ++it) {
    const int idx = t + it * 512;
    const int kk = idx >> 3;
    const int d4 = (idx & 7) * 4;
    const size_t off = (base_i + kk) * CZ + h * CH + d4;
    const us4 kv = *(const us4*)&kb[off];
    *(us4*)&Kl[kk * 36 + d4] = kv;
    const us4 vv = *(const us4*)&vb[off];
    Vt[(d4 + 0) * 388 + kk] = vv[0];
    Vt[(d4 + 1) * 388 + kk] = vv[1];
    Vt[(d4 + 2) * 388 + kk] = vv[2];
    Vt[(d4 + 3) * 388 + kk] = vv[3];
  }
  __syncthreads();

  const int wid = t >> 6;
  const int lane = t & 63;
  const int d = lane & 31;
  const int k0 = (lane >> 5) * 192;
  const float* trih = tri + (size_t)h * NN;

  for (int jj = wid; jj < NRES; jj += 8) {
    float qr[CH];
    const u16* qp = &qb[(base_i + jj) * CZ + h * CH];
    #pragma unroll
    for (int d4 = 0; d4 < CH; d4 += 4) {
      const us4 qv = *(const us4*)&qp[d4];
      qr[d4] = bf2f(qv[0]); qr[d4 + 1] = bf2f(qv[1]);
      qr[d4 + 2] = bf2f(qv[2]); qr[d4 + 3] = bf2f(qv[3]);
    }
    float l[6];
    #pragma unroll
    for (int r = 0; r < 6; ++r) {
      const int kk = lane + 64 * r;
      float acc = 0.f;
      #pragma unroll
      for (int dd = 0; dd < CH; dd += 4) {
        const us4 k4 = *(const us4*)&Kl[kk * 36 + dd];
        acc += qr[dd]     * bf2f(k4[0]);
        acc += qr[dd + 1] * bf2f(k4[1]);
        acc += qr[dd + 2] * bf2f(k4[2]);
        acc += qr[dd + 3] * bf2f(k4[3]);
      }
      l[r] = acc + trih[(size_t)jj * NRES + kk]
                 + 1.0e9f * (ld1<F32>(msk, base_i + kk) - 1.0f);
    }
    float m = l[0];
    #pragma unroll
    for (int r = 1; r < 6; ++r) m = fmaxf(m, l[r]);
    #pragma unroll
    for (int s = 1; s < 64; s <<= 1) m = fmaxf(m, __shfl_xor(m, s, 64));
    float sum = 0.f;
    float e[6];
    #pragma unroll
    for (int r = 0; r < 6; ++r) { e[r] = __expf(l[r] - m); sum += e[r]; }
    #pragma unroll
    for (int s = 1; s < 64; s <<= 1) sum += __shfl_xor(sum, s, 64);
    #pragma unroll
    for (int r = 0; r < 6; ++r) al[wid][lane + 64 * r] = e[r];
    const float inv = 1.0f / sum;
    __syncthreads();

    float o = 0.f;
    #pragma unroll 4
    for (int kx = 0; kx < 192; kx += 4) {
      const int kk = k0 + kx;
      const float4 a4 = *(const float4*)&al[wid][kk];
      const us4 v4 = *(const us4*)&Vt[d * 388 + kk];
      o += a4.x * bf2f(v4[0]) + a4.y * bf2f(v4[1])
         + a4.z * bf2f(v4[2]) + a4.w * bf2f(v4[3]);
    }
    o += __shfl_xor(o, 32, 64);
    if (lane < 32) {
      const size_t oi = (base_i + jj) * CZ + h * CH + d;
      ogb[oi] = f2bf(o * inv * bf2f(gb[oi]));
    }
  }
}

// ---------------------------------------------------------------------------
// K3: out = (o*g) @ w_o + b_o
// ---------------------------------------------------------------------------
template<bool F32>
__global__ __launch_bounds__(256) void k_out(
    const u16* __restrict__ og, const void* __restrict__ wo, const void* __restrict__ bo,
    void* __restrict__ outp, const int* __restrict__ flag)
{
  if ((*flag != 0) != F32) return;
  __shared__ __align__(16) float ol[16][132];
  __shared__ __align__(16) u16 wl[CZ * CZ];
  const int t = threadIdx.x;
  const int rowBase = blockIdx.x * 16;
  const int rloc = t >> 4;
  const int ob = (t & 15) * 8;
  const size_t rowg = (size_t)(rowBase + rloc) * CZ;
  {
    const us8 v = *(const us8*)&og[rowg + ob];
    #pragma unroll
    for (int u = 0; u < 8; ++u) ol[rloc][ob + u] = bf2f(v[u]);
  }
  #pragma unroll
  for (int it = 0; it < 8; ++it) {
    const int idx = (t + it * 256) * 8;
    float tmp[8];
    ld8<F32>(wo, idx, tmp);
    us8 o;
    #pragma unroll
    for (int u = 0; u < 8; ++u) o[u] = f2bf(tmp[u]);
    *(us8*)&wl[idx] = o;
  }
  __syncthreads();
  float acc[8] = {0.f, 0.f, 0.f, 0.f, 0.f, 0.f, 0.f, 0.f};
  #pragma unroll 4
  for (int c = 0; c < CZ; ++c) {
    const float zv = ol[rloc][c];
    const us8 w8 = *(const us8*)&wl[c * CZ + ob];
    #pragma unroll
    for (int u = 0; u < 8; ++u) acc[u] += zv * bf2f(w8[u]);
  }
  #pragma unroll
  for (int u = 0; u < 8; ++u) acc[u] += ld1<F32>(bo, ob + u);
  if constexpr (F32) {
    float* op = (float*)outp;
    #pragma unroll
    for (int u = 0; u < 8; ++u) op[rowg + ob + u] = acc[u];
  } else {
    us8 o8;
    #pragma unroll
    for (int u = 0; u < 8; ++u) o8[u] = f2bf(acc[u]);
    *(us8*)&((u16*)outp)[rowg + ob] = o8;
  }
}

extern "C" void kernel_launch(void* const* d_in, const int* in_sizes, int n_in,
                              void* d_out, int out_size, void* d_ws, size_t ws_size,
                              hipStream_t stream) {
  const void* z     = d_in[0];
  const void* msk   = d_in[1];
  const void* gma   = d_in[2];
  const void* bta   = d_in[3];
  const void* wbias = d_in[4];
  const void* wq    = d_in[5];
  const void* wk    = d_in[6];
  const void* wv    = d_in[7];
  const void* wg    = d_in[8];
  const void* bg    = d_in[9];
  const void* wo    = d_in[10];
  const void* bo    = d_in[11];

  char* ws = (char*)d_ws;
  int* flag = (int*)ws;
  u16* qb = (u16*)(ws + 256);
  u16* kb = qb + NNCZ;
  u16* vb = kb + NNCZ;
  u16* gb = vb + NNCZ;
  float* tri = (float*)(gb + NNCZ);
  u16* ogb = qb;  // alias: q slice consumed by same wave-iteration that writes o

  k_probe<<<dim3(1), dim3(64), 0, stream>>>((const u16*)z, flag);

  k_ln_proj<false><<<dim3(NN / 16), dim3(256), 0, stream>>>(
      z, gma, bta, wbias, wq, wk, wv, wg, bg, qb, kb, vb, gb, tri, flag);
  k_ln_proj<true><<<dim3(NN / 16), dim3(256), 0, stream>>>(
      z, gma, bta, wbias, wq, wk, wv, wg, bg, qb, kb, vb, gb, tri, flag);

  k_attn<false><<<dim3(NRES * NH), dim3(512), 0, stream>>>(
      qb, kb, vb, gb, tri, msk, ogb, flag);
  k_attn<true><<<dim3(NRES * NH), dim3(512), 0, stream>>>(
      qb, kb, vb, gb, tri, msk, ogb, flag);

  k_out<false><<<dim3(NN / 16), dim3(256), 0, stream>>>(ogb, wo, bo, d_out, flag);
  k_out<true><<<dim3(NN / 16), dim3(256), 0, stream>>>(ogb, wo, bo, d_out, flag);
}

// Round 3
// 1165.605 us; speedup vs baseline: 1.3685x; 1.3685x over previous
//
#include <hip/hip_runtime.h>

#define NRES 384
#define CZ 128
#define NH 4
#define CH 32
#define NN (NRES * NRES)
#define NNCZ ((size_t)NN * CZ)

typedef unsigned short u16;
typedef __attribute__((ext_vector_type(4))) unsigned short us4;
typedef __attribute__((ext_vector_type(8))) unsigned short us8;
typedef __attribute__((ext_vector_type(8))) short s8;   // 8 bf16 = MFMA A/B frag
typedef __attribute__((ext_vector_type(4))) float f4;   // MFMA C/D frag

__device__ __forceinline__ float bf2f(u16 u) {
  return __uint_as_float(((unsigned)u) << 16);
}
__device__ __forceinline__ u16 f2bf(float f) {
  unsigned u = __float_as_uint(f);
  u += 0x7fffu + ((u >> 16) & 1u);  // RTNE
  return (u16)(u >> 16);
}

template<bool F32>
__device__ __forceinline__ float ld1(const void* p, size_t i) {
  if constexpr (F32) return ((const float*)p)[i];
  else return bf2f(((const u16*)p)[i]);
}

template<bool F32>
__device__ __forceinline__ void ld8(const void* p, size_t i, float o[8]) {
  if constexpr (F32) {
    const float4 a = *(const float4*)((const float*)p + i);
    const float4 b = *(const float4*)((const float*)p + i + 4);
    o[0] = a.x; o[1] = a.y; o[2] = a.z; o[3] = a.w;
    o[4] = b.x; o[5] = b.y; o[6] = b.z; o[7] = b.w;
  } else {
    const us8 v = *(const us8*)((const u16*)p + i);
    #pragma unroll
    for (int u = 0; u < 8; ++u) o[u] = bf2f(v[u]);
  }
}

// ---------------------------------------------------------------------------
// Probe: decide input dtype from z's exponent-bit statistics.
// ---------------------------------------------------------------------------
__global__ void k_probe(const u16* __restrict__ z, int* __restrict__ flag) {
  int weird = 0;
  for (int i = threadIdx.x; i < 256; i += 64) {
    const int e = (z[i] >> 7) & 0xFF;
    if (e < 0x70 || e > 0x8F) weird++;
  }
  #pragma unroll
  for (int m = 1; m < 64; m <<= 1) weird += __shfl_xor(weird, m, 64);
  if (threadIdx.x == 0) *flag = (weird >= 16) ? 1 : 0;
}

// ---------------------------------------------------------------------------
// K1: LayerNorm + q/k/v/g projections + tri_bias (unchanged from R1).
// ---------------------------------------------------------------------------
template<bool F32>
__global__ __launch_bounds__(256) void k_ln_proj(
    const void* __restrict__ z, const void* __restrict__ gma, const void* __restrict__ bta,
    const void* __restrict__ wbias, const void* __restrict__ wq, const void* __restrict__ wk,
    const void* __restrict__ wv, const void* __restrict__ wg, const void* __restrict__ bg,
    u16* __restrict__ qb, u16* __restrict__ kb, u16* __restrict__ vb, u16* __restrict__ gb,
    float* __restrict__ tri, const int* __restrict__ flag)
{
  if ((*flag != 0) != F32) return;
  __shared__ __align__(16) float zn[16][132];
  __shared__ __align__(16) u16 wl[CZ * CZ];
  const int t = threadIdx.x;
  const int lane = t & 63;
  const int wid = t >> 6;
  const int rowBase = blockIdx.x * 16;

  for (int rr = 0; rr < 4; ++rr) {
    const int rloc = wid * 4 + rr;
    const size_t row = (size_t)(rowBase + rloc);
    const int c0 = lane * 2;
    const float x0 = ld1<F32>(z, row * CZ + c0);
    const float x1 = ld1<F32>(z, row * CZ + c0 + 1);
    float s = x0 + x1;
    float q2 = x0 * x0 + x1 * x1;
    #pragma unroll
    for (int m = 1; m < 64; m <<= 1) {
      s  += __shfl_xor(s, m, 64);
      q2 += __shfl_xor(q2, m, 64);
    }
    const float mu = s * (1.0f / CZ);
    const float rs = rsqrtf(q2 * (1.0f / CZ) - mu * mu + 1e-5f);
    zn[rloc][c0]     = (x0 - mu) * rs * ld1<F32>(gma, c0)     + ld1<F32>(bta, c0);
    zn[rloc][c0 + 1] = (x1 - mu) * rs * ld1<F32>(gma, c0 + 1) + ld1<F32>(bta, c0 + 1);
  }
  __syncthreads();

  const int rloc = t >> 4;
  const int ob = (t & 15) * 8;
  const size_t rowg = (size_t)(rowBase + rloc) * CZ;

  for (int arr = 0; arr < 4; ++arr) {
    const void* W = (arr == 0) ? wq : (arr == 1) ? wk : (arr == 2) ? wv : wg;
    #pragma unroll
    for (int it = 0; it < 8; ++it) {
      const int idx = (t + it * 256) * 8;
      float tmp[8];
      ld8<F32>(W, idx, tmp);
      us8 o;
      #pragma unroll
      for (int u = 0; u < 8; ++u) o[u] = f2bf(tmp[u]);
      *(us8*)&wl[idx] = o;
    }
    __syncthreads();

    float acc[8] = {0.f, 0.f, 0.f, 0.f, 0.f, 0.f, 0.f, 0.f};
    #pragma unroll 4
    for (int c = 0; c < CZ; ++c) {
      const float zv = zn[rloc][c];
      const us8 w8 = *(const us8*)&wl[c * CZ + ob];
      #pragma unroll
      for (int u = 0; u < 8; ++u) acc[u] += zv * bf2f(w8[u]);
    }
    if (arr == 0) {
      #pragma unroll
      for (int u = 0; u < 8; ++u) acc[u] *= 0.17677669529663687f;  // CH^-0.5
    } else if (arr == 3) {
      #pragma unroll
      for (int u = 0; u < 8; ++u) {
        const float x = acc[u] + ld1<F32>(bg, ob + u);
        acc[u] = 1.0f / (1.0f + __expf(-x));
      }
    }
    us8 o8;
    #pragma unroll
    for (int u = 0; u < 8; ++u) o8[u] = f2bf(acc[u]);
    u16* dstb = (arr == 0) ? qb : (arr == 1) ? kb : (arr == 2) ? vb : gb;
    *(us8*)&dstb[rowg + ob] = o8;
    __syncthreads();
  }

  if (t < 64) {
    const int rl = t >> 2, hh = t & 3;
    float acc = 0.f;
    for (int c = 0; c < CZ; ++c) acc += zn[rl][c] * ld1<F32>(wbias, c * NH + hh);
    tri[(size_t)hh * NN + rowBase + rl] = acc;
  }
}

// ---------------------------------------------------------------------------
// K2: MFMA attention. Block = (i,h), 256 thr = 4 waves, wave owns j-tiles
// jt = wid, wid+4, ... (16 queries each). K/V staged in LDS pre-permuted to
// exact 16x16x32 B-fragment order (bank-conflict-free). S in 24 float4 accs;
// softmax in C-layout (row = quad*4+reg, 16-lane shfl reduction); P goes
// C->A layout via per-wave 16x40 LDS chunk buffer. Gating fused.
// ---------------------------------------------------------------------------
template<bool F32>
__global__ __launch_bounds__(256, 3) void k_attn(
    const u16* __restrict__ qb, const u16* __restrict__ kb, const u16* __restrict__ vb,
    const u16* __restrict__ gb, const float* __restrict__ tri, const void* __restrict__ msk,
    u16* __restrict__ ogb, const int* __restrict__ flag)
{
  if ((*flag != 0) != F32) return;
  __shared__ __align__(16) u16 KB[24 * 4 * 16 * 8];  // [tile][quad][n][j]  24576 B
  __shared__ __align__(16) u16 VB[12 * 4 * 32 * 8];  // [chunk][quad][d][j] 24576 B
  __shared__ __align__(16) u16 Pch[4][16 * 40];      // per-wave P chunk     5120 B
  const int t = threadIdx.x;
  const int i = blockIdx.x >> 2;
  const int h = blockIdx.x & 3;
  const size_t base_i = (size_t)i * NRES;

  // Stage K -> KB (B-frag order for S) and V -> VB (B-frag order for PV)
  #pragma unroll
  for (int it = 0; it < 12; ++it) {
    const int idx = t + it * 256;     // 0..3071
    const int kk = idx >> 3;          // key row 0..383
    const int d0 = (idx & 7) * 4;     // d 0..28
    const size_t off = (base_i + kk) * CZ + h * CH + d0;
    const us4 kv = *(const us4*)&kb[off];
    const int tt = kk >> 4, nn = kk & 15, qq = d0 >> 3, jb = d0 & 7;
    *(us4*)&KB[((tt * 4 + qq) * 16 + nn) * 8 + jb] = kv;
    const us4 vv = *(const us4*)&vb[off];
    const int cc = kk >> 5, q2 = (kk >> 3) & 3, jj = kk & 7;
    u16* vdst = &VB[((cc * 4 + q2) * 32 + d0) * 8 + jj];
    vdst[0] = vv[0]; vdst[8] = vv[1]; vdst[16] = vv[2]; vdst[24] = vv[3];
  }
  __syncthreads();

  const int wid = t >> 6;
  const int lane = t & 63;
  const int n = lane & 15;
  const int quad = lane >> 4;
  const float* trih = tri + (size_t)h * NN;
  u16* pb = &Pch[wid][0];

  for (int jt = wid; jt < 24; jt += 4) {
    const int jrow0 = jt * 16;
    // Q A-frag: A[m=n][k=quad*8+j]
    const s8 aq = *(const s8*)&qb[(base_i + jrow0 + n) * CZ + h * CH + quad * 8];

    f4 S[24];
    #pragma unroll
    for (int tt = 0; tt < 24; ++tt) {
      const s8 bk = *(const s8*)&KB[((tt * 4 + quad) * 16 + n) * 8];
      const f4 z4 = {0.f, 0.f, 0.f, 0.f};
      S[tt] = __builtin_amdgcn_mfma_f32_16x16x32_bf16(aq, bk, z4, 0, 0, 0);
    }
    // bias: element (row jrow0+quad*4+r, key tt*16+n)
    #pragma unroll
    for (int tt = 0; tt < 24; ++tt) {
      const int key = tt * 16 + n;
      const float mb = 1.0e9f * (ld1<F32>(msk, base_i + key) - 1.0f);
      const float* tp = &trih[(size_t)(jrow0 + quad * 4) * NRES + key];
      #pragma unroll
      for (int r = 0; r < 4; ++r) S[tt][r] += tp[r * NRES] + mb;
    }
    // softmax: rows live across 16-lane group + 24 tiles
    f4 mx = S[0];
    #pragma unroll
    for (int tt = 1; tt < 24; ++tt) {
      #pragma unroll
      for (int r = 0; r < 4; ++r) mx[r] = fmaxf(mx[r], S[tt][r]);
    }
    #pragma unroll
    for (int s = 1; s < 16; s <<= 1) {
      #pragma unroll
      for (int r = 0; r < 4; ++r) mx[r] = fmaxf(mx[r], __shfl_xor(mx[r], s, 64));
    }
    f4 sum = {0.f, 0.f, 0.f, 0.f};
    #pragma unroll
    for (int tt = 0; tt < 24; ++tt) {
      #pragma unroll
      for (int r = 0; r < 4; ++r) {
        S[tt][r] = __expf(S[tt][r] - mx[r]);
        sum[r] += S[tt][r];
      }
    }
    #pragma unroll
    for (int s = 1; s < 16; s <<= 1) {
      #pragma unroll
      for (int r = 0; r < 4; ++r) sum[r] += __shfl_xor(sum[r], s, 64);
    }
    f4 inv;
    #pragma unroll
    for (int r = 0; r < 4; ++r) inv[r] = 1.0f / sum[r];

    // PV: per 32-key chunk, C->A transform through per-wave LDS buffer
    f4 O0 = {0.f, 0.f, 0.f, 0.f}, O1 = {0.f, 0.f, 0.f, 0.f};
    #pragma unroll
    for (int c = 0; c < 12; ++c) {
      #pragma unroll
      for (int half = 0; half < 2; ++half) {
        const int tt = 2 * c + half;
        #pragma unroll
        for (int r = 0; r < 4; ++r)
          pb[(quad * 4 + r) * 40 + half * 16 + n] = f2bf(S[tt][r]);
      }
      const s8 ap  = *(const s8*)&pb[n * 40 + quad * 8];
      const s8 bv0 = *(const s8*)&VB[((c * 4 + quad) * 32 + n) * 8];
      const s8 bv1 = *(const s8*)&VB[((c * 4 + quad) * 32 + 16 + n) * 8];
      O0 = __builtin_amdgcn_mfma_f32_16x16x32_bf16(ap, bv0, O0, 0, 0, 0);
      O1 = __builtin_amdgcn_mfma_f32_16x16x32_bf16(ap, bv1, O1, 0, 0, 0);
    }
    // epilogue: row = jrow0+quad*4+r, col = dt*16+n; fold 1/sum and gate
    #pragma unroll
    for (int r = 0; r < 4; ++r) {
      const size_t rowoff = (base_i + jrow0 + quad * 4 + r) * CZ + h * CH;
      const float iv = inv[r];
      const float g0 = bf2f(gb[rowoff + n]);
      const float g1 = bf2f(gb[rowoff + 16 + n]);
      ogb[rowoff + n]      = f2bf(O0[r] * iv * g0);
      ogb[rowoff + 16 + n] = f2bf(O1[r] * iv * g1);
    }
  }
}

// ---------------------------------------------------------------------------
// K3: out = (o*g) @ w_o + b_o (unchanged from R1)
// ---------------------------------------------------------------------------
template<bool F32>
__global__ __launch_bounds__(256) void k_out(
    const u16* __restrict__ og, const void* __restrict__ wo, const void* __restrict__ bo,
    void* __restrict__ outp, const int* __restrict__ flag)
{
  if ((*flag != 0) != F32) return;
  __shared__ __align__(16) float ol[16][132];
  __shared__ __align__(16) u16 wl[CZ * CZ];
  const int t = threadIdx.x;
  const int rowBase = blockIdx.x * 16;
  const int rloc = t >> 4;
  const int ob = (t & 15) * 8;
  const size_t rowg = (size_t)(rowBase + rloc) * CZ;
  {
    const us8 v = *(const us8*)&og[rowg + ob];
    #pragma unroll
    for (int u = 0; u < 8; ++u) ol[rloc][ob + u] = bf2f(v[u]);
  }
  #pragma unroll
  for (int it = 0; it < 8; ++it) {
    const int idx = (t + it * 256) * 8;
    float tmp[8];
    ld8<F32>(wo, idx, tmp);
    us8 o;
    #pragma unroll
    for (int u = 0; u < 8; ++u) o[u] = f2bf(tmp[u]);
    *(us8*)&wl[idx] = o;
  }
  __syncthreads();
  float acc[8] = {0.f, 0.f, 0.f, 0.f, 0.f, 0.f, 0.f, 0.f};
  #pragma unroll 4
  for (int c = 0; c < CZ; ++c) {
    const float zv = ol[rloc][c];
    const us8 w8 = *(const us8*)&wl[c * CZ + ob];
    #pragma unroll
    for (int u = 0; u < 8; ++u) acc[u] += zv * bf2f(w8[u]);
  }
  #pragma unroll
  for (int u = 0; u < 8; ++u) acc[u] += ld1<F32>(bo, ob + u);
  if constexpr (F32) {
    float* op = (float*)outp;
    #pragma unroll
    for (int u = 0; u < 8; ++u) op[rowg + ob + u] = acc[u];
  } else {
    us8 o8;
    #pragma unroll
    for (int u = 0; u < 8; ++u) o8[u] = f2bf(acc[u]);
    *(us8*)&((u16*)outp)[rowg + ob] = o8;
  }
}

extern "C" void kernel_launch(void* const* d_in, const int* in_sizes, int n_in,
                              void* d_out, int out_size, void* d_ws, size_t ws_size,
                              hipStream_t stream) {
  const void* z     = d_in[0];
  const void* msk   = d_in[1];
  const void* gma   = d_in[2];
  const void* bta   = d_in[3];
  const void* wbias = d_in[4];
  const void* wq    = d_in[5];
  const void* wk    = d_in[6];
  const void* wv    = d_in[7];
  const void* wg    = d_in[8];
  const void* bg    = d_in[9];
  const void* wo    = d_in[10];
  const void* bo    = d_in[11];

  char* ws = (char*)d_ws;
  int* flag = (int*)ws;
  u16* qb = (u16*)(ws + 256);
  u16* kb = qb + NNCZ;
  u16* vb = kb + NNCZ;
  u16* gb = vb + NNCZ;
  float* tri = (float*)(gb + NNCZ);
  u16* ogb = qb;  // alias: q slice consumed by the same wave-iteration that writes o

  k_probe<<<dim3(1), dim3(64), 0, stream>>>((const u16*)z, flag);

  k_ln_proj<false><<<dim3(NN / 16), dim3(256), 0, stream>>>(
      z, gma, bta, wbias, wq, wk, wv, wg, bg, qb, kb, vb, gb, tri, flag);
  k_ln_proj<true><<<dim3(NN / 16), dim3(256), 0, stream>>>(
      z, gma, bta, wbias, wq, wk, wv, wg, bg, qb, kb, vb, gb, tri, flag);

  k_attn<false><<<dim3(NRES * NH), dim3(256), 0, stream>>>(
      qb, kb, vb, gb, tri, msk, ogb, flag);
  k_attn<true><<<dim3(NRES * NH), dim3(256), 0, stream>>>(
      qb, kb, vb, gb, tri, msk, ogb, flag);

  k_out<false><<<dim3(NN / 16), dim3(256), 0, stream>>>(ogb, wo, bo, d_out, flag);
  k_out<true><<<dim3(NN / 16), dim3(256), 0, stream>>>(ogb, wo, bo, d_out, flag);
}

// Round 4
// 517.784 us; speedup vs baseline: 3.0807x; 2.2511x over previous
//
#include <hip/hip_runtime.h>

#define NRES 384
#define CZ 128
#define NH 4
#define CH 32
#define NN (NRES * NRES)
#define NNCZ ((size_t)NN * CZ)

typedef unsigned short u16;
typedef __attribute__((ext_vector_type(4))) unsigned short us4;
typedef __attribute__((ext_vector_type(8))) unsigned short us8;
typedef __attribute__((ext_vector_type(8))) short s8;   // 8 bf16 = MFMA A/B frag
typedef __attribute__((ext_vector_type(4))) float f4;   // MFMA C/D frag

__device__ __forceinline__ float bf2f(u16 u) {
  return __uint_as_float(((unsigned)u) << 16);
}
__device__ __forceinline__ u16 f2bf(float f) {
  unsigned u = __float_as_uint(f);
  u += 0x7fffu + ((u >> 16) & 1u);  // RTNE
  return (u16)(u >> 16);
}

template<bool F32>
__device__ __forceinline__ float ld1(const void* p, size_t i) {
  if constexpr (F32) return ((const float*)p)[i];
  else return bf2f(((const u16*)p)[i]);
}

template<bool F32>
__device__ __forceinline__ void ld4v(const void* p, size_t i, float o[4]) {
  if constexpr (F32) {
    const float4 a = *(const float4*)((const float*)p + i);
    o[0] = a.x; o[1] = a.y; o[2] = a.z; o[3] = a.w;
  } else {
    const us4 v = *(const us4*)((const u16*)p + i);
    #pragma unroll
    for (int u = 0; u < 4; ++u) o[u] = bf2f(v[u]);
  }
}

template<bool F32>
__device__ __forceinline__ void ld8(const void* p, size_t i, float o[8]) {
  if constexpr (F32) {
    const float4 a = *(const float4*)((const float*)p + i);
    const float4 b = *(const float4*)((const float*)p + i + 4);
    o[0] = a.x; o[1] = a.y; o[2] = a.z; o[3] = a.w;
    o[4] = b.x; o[5] = b.y; o[6] = b.z; o[7] = b.w;
  } else {
    const us8 v = *(const us8*)((const u16*)p + i);
    #pragma unroll
    for (int u = 0; u < 8; ++u) o[u] = bf2f(v[u]);
  }
}

// ---------------------------------------------------------------------------
// Probe: decide input dtype from z's exponent-bit statistics.
// ---------------------------------------------------------------------------
__global__ void k_probe(const u16* __restrict__ z, int* __restrict__ flag) {
  int weird = 0;
  for (int i = threadIdx.x; i < 256; i += 64) {
    const int e = (z[i] >> 7) & 0xFF;
    if (e < 0x70 || e > 0x8F) weird++;
  }
  #pragma unroll
  for (int m = 1; m < 64; m <<= 1) weird += __shfl_xor(weird, m, 64);
  if (threadIdx.x == 0) *flag = (weird >= 16) ? 1 : 0;
}

// ---------------------------------------------------------------------------
// K1: LayerNorm + MFMA projections + tri_bias (transposed out).
// Block = 128 rows, 256 thr = 4 waves.
//   LN: 16-lane-group shuffles, zn -> LDS bf16 row-major (stride 136).
//   Per weight (q,k,v,g): stage W^T in A-frag order; C = W^T @ zn^T via
//   16x16x32 MFMA: wave = 2 m-tiles x 8 n-tiles x 4 K-steps. C reg index runs
//   along out-channels -> us4 (8 B) packed stores.
//   tri stored TRANSPOSED: triT[h][key][qrow] for k_attn float4 bias loads.
// ---------------------------------------------------------------------------
template<bool F32>
__global__ __launch_bounds__(256, 2) void k_ln_proj(
    const void* __restrict__ z, const void* __restrict__ gma, const void* __restrict__ bta,
    const void* __restrict__ wbias, const void* __restrict__ wq, const void* __restrict__ wk,
    const void* __restrict__ wv, const void* __restrict__ wg, const void* __restrict__ bg,
    u16* __restrict__ qb, u16* __restrict__ kb, u16* __restrict__ vb, u16* __restrict__ gb,
    float* __restrict__ triT, const int* __restrict__ flag)
{
  if ((*flag != 0) != F32) return;
  __shared__ __align__(16) u16 znl[128 * 136];   // 34816 B
  __shared__ __align__(16) u16 WT[CZ * CZ];      // 32768 B, A-frag order
  const int t = threadIdx.x;
  const int lane = t & 63;
  const int wid = t >> 6;
  const int n16 = lane & 15;
  const int quad = lane >> 4;   // also LN row-group
  const int rowBase = blockIdx.x * 128;

  // ---- LayerNorm ----
  const int c0 = n16 * 8;
  float g8[8], b8[8];
  ld8<F32>(gma, c0, g8);
  ld8<F32>(bta, c0, b8);
  for (int it = 0; it < 8; ++it) {
    const int rl = wid * 32 + it * 4 + quad;
    float x[8];
    ld8<F32>(z, (size_t)(rowBase + rl) * CZ + c0, x);
    float s = 0.f, q2 = 0.f;
    #pragma unroll
    for (int u = 0; u < 8; ++u) { s += x[u]; q2 += x[u] * x[u]; }
    #pragma unroll
    for (int m = 1; m < 16; m <<= 1) {
      s  += __shfl_xor(s, m, 64);
      q2 += __shfl_xor(q2, m, 64);
    }
    const float mu = s * (1.0f / CZ);
    const float rs = rsqrtf(q2 * (1.0f / CZ) - mu * mu + 1e-5f);
    us8 o;
    #pragma unroll
    for (int u = 0; u < 8; ++u) o[u] = f2bf((x[u] - mu) * rs * g8[u] + b8[u]);
    *(us8*)&znl[rl * 136 + c0] = o;
  }
  __syncthreads();

  // ---- tri_bias (VALU; tiny). wb columns for this lane's channels in regs.
  float wb4[8][4];
  #pragma unroll
  for (int cc = 0; cc < 8; ++cc) ld4v<F32>(wbias, (size_t)(c0 + cc) * NH, wb4[cc]);
  for (int it = 0; it < 8; ++it) {
    const int rl = wid * 32 + it * 4 + quad;
    const us8 zv8 = *(const us8*)&znl[rl * 136 + c0];
    float a0 = 0.f, a1 = 0.f, a2 = 0.f, a3 = 0.f;
    #pragma unroll
    for (int cc = 0; cc < 8; ++cc) {
      const float zv = bf2f(zv8[cc]);
      a0 += zv * wb4[cc][0]; a1 += zv * wb4[cc][1];
      a2 += zv * wb4[cc][2]; a3 += zv * wb4[cc][3];
    }
    #pragma unroll
    for (int m = 1; m < 16; m <<= 1) {
      a0 += __shfl_xor(a0, m, 64); a1 += __shfl_xor(a1, m, 64);
      a2 += __shfl_xor(a2, m, 64); a3 += __shfl_xor(a3, m, 64);
    }
    if (n16 < 4) {
      const float v = (n16 == 0) ? a0 : (n16 == 1) ? a1 : (n16 == 2) ? a2 : a3;
      const int P = rowBase + rl;
      const int aI = P / NRES, bI = P % NRES;   // pair (qrow=aI, key=bI)
      triT[(size_t)n16 * NN + (size_t)bI * NRES + aI] = v;
    }
  }

  // ---- 4 projection GEMMs ----
  const u16 scl_q = 1;  // marker only
  for (int arr = 0; arr < 4; ++arr) {
    const void* W = (arr == 0) ? wq : (arr == 1) ? wk : (arr == 2) ? wv : wg;
    __syncthreads();   // prior MFMA reads of WT done
    // stage W^T in A-frag order: element (m=outch, k=c) at
    // WT[ks*4096 + ((mt*4+quad)*16 + (m&15))*8 + j],  c = ks*32+quad*8+j
    #pragma unroll
    for (int it = 0; it < 16; ++it) {
      const int c = (t >> 5) + it * 8;
      const int m0 = (t & 31) * 4;
      float w4[4];
      ld4v<F32>(W, (size_t)c * CZ + m0, w4);
      const int ks = c >> 5, qq = (c >> 3) & 3, j = c & 7;
      #pragma unroll
      for (int mm = 0; mm < 4; ++mm) {
        const int m = m0 + mm;
        WT[ks * 4096 + (((m >> 4) * 4 + qq) * 16 + (m & 15)) * 8 + j] = f2bf(w4[mm]);
      }
    }
    __syncthreads();

    f4 acc[2][8];
    #pragma unroll
    for (int i = 0; i < 2; ++i)
      #pragma unroll
      for (int nt = 0; nt < 8; ++nt) acc[i][nt] = f4{0.f, 0.f, 0.f, 0.f};

    #pragma unroll
    for (int ks = 0; ks < 4; ++ks) {
      s8 a[2], b[8];
      #pragma unroll
      for (int i = 0; i < 2; ++i)
        a[i] = *(const s8*)&WT[ks * 4096 + (((wid * 2 + i) * 4 + quad) * 16 + n16) * 8];
      #pragma unroll
      for (int nt = 0; nt < 8; ++nt)
        b[nt] = *(const s8*)&znl[(nt * 16 + n16) * 136 + ks * 32 + quad * 8];
      #pragma unroll
      for (int i = 0; i < 2; ++i)
        #pragma unroll
        for (int nt = 0; nt < 8; ++nt)
          acc[i][nt] = __builtin_amdgcn_mfma_f32_16x16x32_bf16(a[i], b[nt], acc[i][nt], 0, 0, 0);
    }

    u16* dstb = (arr == 0) ? qb : (arr == 1) ? kb : (arr == 2) ? vb : gb;
    #pragma unroll
    for (int i = 0; i < 2; ++i) {
      const int mt = wid * 2 + i;
      const int och0 = mt * 16 + quad * 4;
      float e4[4];
      if (arr == 3) ld4v<F32>(bg, och0, e4);
      #pragma unroll
      for (int nt = 0; nt < 8; ++nt) {
        us4 o;
        #pragma unroll
        for (int r = 0; r < 4; ++r) {
          float v = acc[i][nt][r];
          if (arr == 0) v *= 0.17677669529663687f;           // CH^-0.5
          else if (arr == 3) v = 1.0f / (1.0f + __expf(-(v + e4[r])));
          o[r] = f2bf(v);
        }
        *(us4*)&dstb[(size_t)(rowBase + nt * 16 + n16) * CZ + och0] = o;
      }
    }
  }
  (void)scl_q;
}

// ---------------------------------------------------------------------------
// K2: MFMA attention (as R2) + transposed-tri float4 bias + hoisted mask.
// ---------------------------------------------------------------------------
template<bool F32>
__global__ __launch_bounds__(256, 3) void k_attn(
    const u16* __restrict__ qb, const u16* __restrict__ kb, const u16* __restrict__ vb,
    const u16* __restrict__ gb, const float* __restrict__ triT, const void* __restrict__ msk,
    u16* __restrict__ ogb, const int* __restrict__ flag)
{
  if ((*flag != 0) != F32) return;
  __shared__ __align__(16) u16 KB[24 * 4 * 16 * 8];  // [tile][quad][n][j]
  __shared__ __align__(16) u16 VB[12 * 4 * 32 * 8];  // [chunk][quad][d][j]
  __shared__ __align__(16) u16 Pch[4][16 * 40];      // per-wave P chunk
  const int t = threadIdx.x;
  const int i = blockIdx.x >> 2;
  const int h = blockIdx.x & 3;
  const size_t base_i = (size_t)i * NRES;

  #pragma unroll
  for (int it = 0; it < 12; ++it) {
    const int idx = t + it * 256;
    const int kk = idx >> 3;
    const int d0 = (idx & 7) * 4;
    const size_t off = (base_i + kk) * CZ + h * CH + d0;
    const us4 kv = *(const us4*)&kb[off];
    const int tt = kk >> 4, nn = kk & 15, qq = d0 >> 3, jb = d0 & 7;
    *(us4*)&KB[((tt * 4 + qq) * 16 + nn) * 8 + jb] = kv;
    const us4 vv = *(const us4*)&vb[off];
    const int cc = kk >> 5, q2 = (kk >> 3) & 3, jj = kk & 7;
    u16* vdst = &VB[((cc * 4 + q2) * 32 + d0) * 8 + jj];
    vdst[0] = vv[0]; vdst[8] = vv[1]; vdst[16] = vv[2]; vdst[24] = vv[3];
  }
  __syncthreads();

  const int wid = t >> 6;
  const int lane = t & 63;
  const int n = lane & 15;
  const int quad = lane >> 4;
  const float* trih = triT + (size_t)h * NN;
  u16* pb = &Pch[wid][0];

  // mask bias hoisted: same keys for every j-tile of this wave
  float mb[24];
  #pragma unroll
  for (int tt = 0; tt < 24; ++tt)
    mb[tt] = 1.0e9f * (ld1<F32>(msk, base_i + tt * 16 + n) - 1.0f);

  for (int jt = wid; jt < 24; jt += 4) {
    const int jrow0 = jt * 16;
    const s8 aq = *(const s8*)&qb[(base_i + jrow0 + n) * CZ + h * CH + quad * 8];

    f4 S[24];
    #pragma unroll
    for (int tt = 0; tt < 24; ++tt) {
      const s8 bk = *(const s8*)&KB[((tt * 4 + quad) * 16 + n) * 8];
      const f4 z4 = {0.f, 0.f, 0.f, 0.f};
      S[tt] = __builtin_amdgcn_mfma_f32_16x16x32_bf16(aq, bk, z4, 0, 0, 0);
    }
    #pragma unroll
    for (int tt = 0; tt < 24; ++tt) {
      const float4 t4 = *(const float4*)&trih[(size_t)(tt * 16 + n) * NRES + jrow0 + quad * 4];
      S[tt][0] += t4.x + mb[tt];
      S[tt][1] += t4.y + mb[tt];
      S[tt][2] += t4.z + mb[tt];
      S[tt][3] += t4.w + mb[tt];
    }
    f4 mx = S[0];
    #pragma unroll
    for (int tt = 1; tt < 24; ++tt) {
      #pragma unroll
      for (int r = 0; r < 4; ++r) mx[r] = fmaxf(mx[r], S[tt][r]);
    }
    #pragma unroll
    for (int s = 1; s < 16; s <<= 1) {
      #pragma unroll
      for (int r = 0; r < 4; ++r) mx[r] = fmaxf(mx[r], __shfl_xor(mx[r], s, 64));
    }
    f4 sum = {0.f, 0.f, 0.f, 0.f};
    #pragma unroll
    for (int tt = 0; tt < 24; ++tt) {
      #pragma unroll
      for (int r = 0; r < 4; ++r) {
        S[tt][r] = __expf(S[tt][r] - mx[r]);
        sum[r] += S[tt][r];
      }
    }
    #pragma unroll
    for (int s = 1; s < 16; s <<= 1) {
      #pragma unroll
      for (int r = 0; r < 4; ++r) sum[r] += __shfl_xor(sum[r], s, 64);
    }
    f4 inv;
    #pragma unroll
    for (int r = 0; r < 4; ++r) inv[r] = 1.0f / sum[r];

    f4 O0 = {0.f, 0.f, 0.f, 0.f}, O1 = {0.f, 0.f, 0.f, 0.f};
    #pragma unroll
    for (int c = 0; c < 12; ++c) {
      #pragma unroll
      for (int half = 0; half < 2; ++half) {
        const int tt = 2 * c + half;
        #pragma unroll
        for (int r = 0; r < 4; ++r)
          pb[(quad * 4 + r) * 40 + half * 16 + n] = f2bf(S[tt][r]);
      }
      const s8 ap  = *(const s8*)&pb[n * 40 + quad * 8];
      const s8 bv0 = *(const s8*)&VB[((c * 4 + quad) * 32 + n) * 8];
      const s8 bv1 = *(const s8*)&VB[((c * 4 + quad) * 32 + 16 + n) * 8];
      O0 = __builtin_amdgcn_mfma_f32_16x16x32_bf16(ap, bv0, O0, 0, 0, 0);
      O1 = __builtin_amdgcn_mfma_f32_16x16x32_bf16(ap, bv1, O1, 0, 0, 0);
    }
    #pragma unroll
    for (int r = 0; r < 4; ++r) {
      const size_t rowoff = (base_i + jrow0 + quad * 4 + r) * CZ + h * CH;
      const float iv = inv[r];
      const float g0 = bf2f(gb[rowoff + n]);
      const float g1 = bf2f(gb[rowoff + 16 + n]);
      ogb[rowoff + n]      = f2bf(O0[r] * iv * g0);
      ogb[rowoff + 16 + n] = f2bf(O1[r] * iv * g1);
    }
  }
}

// ---------------------------------------------------------------------------
// K3: out = (o*g) @ w_o + b_o — same MFMA structure as one k_ln_proj weight.
// ---------------------------------------------------------------------------
template<bool F32>
__global__ __launch_bounds__(256, 2) void k_out(
    const u16* __restrict__ og, const void* __restrict__ wo, const void* __restrict__ bo,
    void* __restrict__ outp, const int* __restrict__ flag)
{
  if ((*flag != 0) != F32) return;
  __shared__ __align__(16) u16 ol[128 * 136];
  __shared__ __align__(16) u16 WT[CZ * CZ];
  const int t = threadIdx.x;
  const int lane = t & 63;
  const int wid = t >> 6;
  const int n16 = lane & 15;
  const int quad = lane >> 4;
  const int rowBase = blockIdx.x * 128;

  #pragma unroll
  for (int it = 0; it < 8; ++it) {
    const int idx8 = t + it * 256;
    const int r = idx8 >> 4;
    const int c0 = (idx8 & 15) * 8;
    *(us8*)&ol[r * 136 + c0] = *(const us8*)&og[(size_t)(rowBase + r) * CZ + c0];
  }
  #pragma unroll
  for (int it = 0; it < 16; ++it) {
    const int c = (t >> 5) + it * 8;
    const int m0 = (t & 31) * 4;
    float w4[4];
    ld4v<F32>(wo, (size_t)c * CZ + m0, w4);
    const int ks = c >> 5, qq = (c >> 3) & 3, j = c & 7;
    #pragma unroll
    for (int mm = 0; mm < 4; ++mm) {
      const int m = m0 + mm;
      WT[ks * 4096 + (((m >> 4) * 4 + qq) * 16 + (m & 15)) * 8 + j] = f2bf(w4[mm]);
    }
  }
  __syncthreads();

  f4 acc[2][8];
  #pragma unroll
  for (int i = 0; i < 2; ++i)
    #pragma unroll
    for (int nt = 0; nt < 8; ++nt) acc[i][nt] = f4{0.f, 0.f, 0.f, 0.f};

  #pragma unroll
  for (int ks = 0; ks < 4; ++ks) {
    s8 a[2], b[8];
    #pragma unroll
    for (int i = 0; i < 2; ++i)
      a[i] = *(const s8*)&WT[ks * 4096 + (((wid * 2 + i) * 4 + quad) * 16 + n16) * 8];
    #pragma unroll
    for (int nt = 0; nt < 8; ++nt)
      b[nt] = *(const s8*)&ol[(nt * 16 + n16) * 136 + ks * 32 + quad * 8];
    #pragma unroll
    for (int i = 0; i < 2; ++i)
      #pragma unroll
      for (int nt = 0; nt < 8; ++nt)
        acc[i][nt] = __builtin_amdgcn_mfma_f32_16x16x32_bf16(a[i], b[nt], acc[i][nt], 0, 0, 0);
  }

  #pragma unroll
  for (int i = 0; i < 2; ++i) {
    const int och0 = (wid * 2 + i) * 16 + quad * 4;
    float b4[4];
    ld4v<F32>(bo, och0, b4);
    #pragma unroll
    for (int nt = 0; nt < 8; ++nt) {
      const size_t off = (size_t)(rowBase + nt * 16 + n16) * CZ + och0;
      if constexpr (F32) {
        float4 o;
        o.x = acc[i][nt][0] + b4[0]; o.y = acc[i][nt][1] + b4[1];
        o.z = acc[i][nt][2] + b4[2]; o.w = acc[i][nt][3] + b4[3];
        *(float4*)&((float*)outp)[off] = o;
      } else {
        us4 o;
        #pragma unroll
        for (int r = 0; r < 4; ++r) o[r] = f2bf(acc[i][nt][r] + b4[r]);
        *(us4*)&((u16*)outp)[off] = o;
      }
    }
  }
}

extern "C" void kernel_launch(void* const* d_in, const int* in_sizes, int n_in,
                              void* d_out, int out_size, void* d_ws, size_t ws_size,
                              hipStream_t stream) {
  const void* z     = d_in[0];
  const void* msk   = d_in[1];
  const void* gma   = d_in[2];
  const void* bta   = d_in[3];
  const void* wbias = d_in[4];
  const void* wq    = d_in[5];
  const void* wk    = d_in[6];
  const void* wv    = d_in[7];
  const void* wg    = d_in[8];
  const void* bg    = d_in[9];
  const void* wo    = d_in[10];
  const void* bo    = d_in[11];

  char* ws = (char*)d_ws;
  int* flag = (int*)ws;
  u16* qb = (u16*)(ws + 256);
  u16* kb = qb + NNCZ;
  u16* vb = kb + NNCZ;
  u16* gb = vb + NNCZ;
  float* triT = (float*)(gb + NNCZ);
  u16* ogb = qb;  // alias: q slice consumed by the same wave-iteration that writes o

  k_probe<<<dim3(1), dim3(64), 0, stream>>>((const u16*)z, flag);

  k_ln_proj<false><<<dim3(NN / 128), dim3(256), 0, stream>>>(
      z, gma, bta, wbias, wq, wk, wv, wg, bg, qb, kb, vb, gb, triT, flag);
  k_ln_proj<true><<<dim3(NN / 128), dim3(256), 0, stream>>>(
      z, gma, bta, wbias, wq, wk, wv, wg, bg, qb, kb, vb, gb, triT, flag);

  k_attn<false><<<dim3(NRES * NH), dim3(256), 0, stream>>>(
      qb, kb, vb, gb, triT, msk, ogb, flag);
  k_attn<true><<<dim3(NRES * NH), dim3(256), 0, stream>>>(
      qb, kb, vb, gb, triT, msk, ogb, flag);

  k_out<false><<<dim3(NN / 128), dim3(256), 0, stream>>>(ogb, wo, bo, d_out, flag);
  k_out<true><<<dim3(NN / 128), dim3(256), 0, stream>>>(ogb, wo, bo, d_out, flag);
}